// Round 7
// baseline (87.761 us; speedup 1.0000x reference)
//
#include <hip/hip_runtime.h>
#include <hip/hip_bf16.h>
#include <math.h>

#define NB 512
#define NT 256
#define NC 384
#define NH 64

typedef __bf16 bf16x8 __attribute__((ext_vector_type(8)));
typedef unsigned short u16x8 __attribute__((ext_vector_type(8)));
typedef unsigned short u16x4 __attribute__((ext_vector_type(4)));
typedef unsigned int   u32x4 __attribute__((ext_vector_type(4)));
typedef float f32x4 __attribute__((ext_vector_type(4)));

__device__ __forceinline__ unsigned short f2bf(float f) {
    union { float f; unsigned u; } v; v.f = f;
    unsigned r = v.u + 0x7FFFu + ((v.u >> 16) & 1u);   // round-to-nearest-even
    return (unsigned short)(r >> 16);
}

__device__ __forceinline__ f32x4 mfma16(bf16x8 a, bf16x8 b, f32x4 c) {
    return __builtin_amdgcn_mfma_f32_16x16x32_bf16(a, b, c, 0, 0, 0);
}

// ============ kernel 1: W -> Wf (bf16, MFMA B-fragment packed) =================
// Wf element e = ((n*12+kk)*64 + l)*8 + j  holds  W_m[c=kk*32+8*(l>>4)+j][h=(n&3)*16+(l&15)]
// (verified in rounds 4/5/6)
__global__ void prep_w(const float* __restrict__ Wq, const float* __restrict__ Wk,
                       const float* __restrict__ Wv, unsigned short* __restrict__ Wf) {
    const int e = blockIdx.x * 256 + threadIdx.x;   // 0..73727
    const int j  = e & 7;
    const int l  = (e >> 3) & 63;
    const int fi = e >> 9;                          // 0..143
    const int kk = fi % 12;
    const int n  = fi / 12;
    const int g = l >> 4, col = l & 15;
    const int c = kk * 32 + g * 8 + j;
    const int h = (n & 3) * 16 + col;
    const float* W = (n < 4) ? Wq : (n < 8 ? Wk : Wv);
    Wf[e] = f2bf(W[c * 64 + h]);
}

// ============ kernel 2: fully fused head, 16 waves (1024 thr) ==================
// One block per batch. Wave w owns q-tile MT = w. LDS regions (shorts):
//   Q  [256][72]   @ 0        (rows; read back as B-frags)
//   K  [256][72]   @ 18432
//   VT [64][264]   @ 36864    (V transposed)
//   XS [64][392]   @ 53760    (coalesced x staging, 4 chunks of 64 rows)
#define FOFF_Q   0
#define FLDQK    72
#define FOFF_K   18432
#define FOFF_VT  36864
#define FLDVT    264
#define FOFF_XS  53760
#define FLDXS    392
#define FSMEM    78848          // shorts = 157,696 B -> 1 block/CU, 16 waves

__global__ __launch_bounds__(1024, 4) void head_v4(
    const float* __restrict__ x, const unsigned short* __restrict__ Wf,
    float* __restrict__ out)
{
    __shared__ __align__(16) unsigned short SM[FSMEM];

    const int b    = blockIdx.x;
    const int tid  = threadIdx.x;
    const int w    = tid >> 6;       // wave 0..15 == q-tile MT
    const int lane = tid & 63;
    const int g    = lane >> 4;
    const int col  = lane & 15;
    const int MT   = w;

    // ---------------- phase 1: coalesced x staging -> A-frags in regs --------
    bf16x8 xfrag[12];
    #pragma unroll
    for (int ch = 0; ch < 4; ++ch) {
        const float* xb = x + ((size_t)b * NT + ch * 64) * NC;
        #pragma unroll
        for (int k = 0; k < 3; ++k) {
            const int idx = k * 8192 + tid * 8;     // 1024 thr x 8 f32
            const int row = idx / 384;              // 0..63 (384 % 8 == 0)
            const int cc  = idx - row * 384;
            const float4 f0 = *reinterpret_cast<const float4*>(xb + idx);
            const float4 f1 = *reinterpret_cast<const float4*>(xb + idx + 4);
            u16x8 u;
            u[0] = f2bf(f0.x); u[1] = f2bf(f0.y); u[2] = f2bf(f0.z); u[3] = f2bf(f0.w);
            u[4] = f2bf(f1.x); u[5] = f2bf(f1.y); u[6] = f2bf(f1.z); u[7] = f2bf(f1.w);
            *reinterpret_cast<u16x8*>(&SM[FOFF_XS + row * FLDXS + cc]) = u;
        }
        __syncthreads();
        if ((MT >> 2) == ch) {                      // wave-uniform
            const int lr = (MT & 3) * 16 + col;     // local row in chunk
            #pragma unroll
            for (int kk = 0; kk < 12; ++kk)
                xfrag[kk] = *reinterpret_cast<const bf16x8*>(
                    &SM[FOFF_XS + lr * FLDXS + kk * 32 + g * 8]);
        }
        __syncthreads();
    }

    // ---------------- phase 2: Q/K/V projection (B-frags from packed Wf) -----
    #pragma unroll
    for (int pass = 0; pass < 3; ++pass) {
        f32x4 acc[4];
        #pragma unroll
        for (int n = 0; n < 4; ++n) acc[n] = (f32x4){0.f, 0.f, 0.f, 0.f};
        #pragma unroll
        for (int kk = 0; kk < 12; ++kk) {
            bf16x8 bb[4];
            #pragma unroll
            for (int n = 0; n < 4; ++n)
                bb[n] = *reinterpret_cast<const bf16x8*>(
                    Wf + ((size_t)((pass * 4 + n) * 12 + kk) * 64 + lane) * 8);
            #pragma unroll
            for (int n = 0; n < 4; ++n)
                acc[n] = mfma16(xfrag[kk], bb[n], acc[n]);
        }
        const int tb = MT * 16 + g * 4;
        if (pass < 2) {
            const int base = (pass == 0) ? FOFF_Q : FOFF_K;
            #pragma unroll
            for (int n = 0; n < 4; ++n)
                #pragma unroll
                for (int r = 0; r < 4; ++r)
                    SM[base + (tb + r) * FLDQK + n * 16 + col] = f2bf(acc[n][r]);
        } else {
            #pragma unroll
            for (int n = 0; n < 4; ++n)
                #pragma unroll
                for (int r = 0; r < 4; ++r)
                    SM[FOFF_VT + (n * 16 + col) * FLDVT + tb + r] = f2bf(acc[n][r]);
        }
    }
    __syncthreads();   // Q/K/VT visible block-wide; no more barriers below

    // ---------------- phase 3: attention (swapped QK^T, shuffle PV) ----------
    const int hi_half = (lane >> 5) & 1;
    const int srcA = ((lane >> 4) & 1) * 32 + col;
    const int srcB = srcA + 16;

    // Q B-frags from LDS rows
    bf16x8 qb[2];
    #pragma unroll
    for (int kk = 0; kk < 2; ++kk)
        qb[kk] = *reinterpret_cast<const bf16x8*>(
            &SM[FOFF_Q + (MT * 16 + col) * FLDQK + kk * 32 + g * 8]);

    // scores S^T: lane holds S[s=nt*16+4g+r][t=MT*16+col]
    f32x4 sc[16];
    #pragma unroll
    for (int nt = 0; nt < 16; ++nt) {
        if (nt <= MT) {
            f32x4 a = {0.f, 0.f, 0.f, 0.f};
            const bf16x8 ka0 = *reinterpret_cast<const bf16x8*>(
                &SM[FOFF_K + (nt * 16 + col) * FLDQK + g * 8]);
            const bf16x8 ka1 = *reinterpret_cast<const bf16x8*>(
                &SM[FOFF_K + (nt * 16 + col) * FLDQK + 32 + g * 8]);
            a = mfma16(ka0, qb[0], a);
            a = mfma16(ka1, qb[1], a);
            sc[nt] = a;
        }
    }

    // softmax over s for row t=col; reduce across g with 2 shuffles
    float m = -INFINITY;
    #pragma unroll
    for (int nt = 0; nt < 16; ++nt) {
        if (nt <= MT) {
            #pragma unroll
            for (int r = 0; r < 4; ++r) {
                float v = sc[nt][r] * 0.125f;
                if (nt == MT && (4 * g + r) > col) v = -INFINITY;   // causal
                sc[nt][r] = v;
                m = fmaxf(m, v);
            }
        }
    }
    m = fmaxf(m, __shfl_xor(m, 16));
    m = fmaxf(m, __shfl_xor(m, 32));
    float s = 0.f;
    #pragma unroll
    for (int nt = 0; nt < 16; ++nt) {
        if (nt <= MT) {
            #pragma unroll
            for (int r = 0; r < 4; ++r) {
                const float p = __expf(sc[nt][r] - m);
                sc[nt][r] = p;
                s += p;
            }
        }
    }
    s += __shfl_xor(s, 16);
    s += __shfl_xor(s, 32);
    const float inv = 1.0f / s;

    // normalized P -> bf16 pairs (per nt: r0|r1, r2|r3)
    unsigned P4lo[16], P4hi[16];
    #pragma unroll
    for (int nt = 0; nt < 16; ++nt) {
        if (nt <= MT) {
            P4lo[nt] = (unsigned)f2bf(sc[nt][0] * inv) |
                       ((unsigned)f2bf(sc[nt][1] * inv) << 16);
            P4hi[nt] = (unsigned)f2bf(sc[nt][2] * inv) |
                       ((unsigned)f2bf(sc[nt][3] * inv) << 16);
        } else { P4lo[nt] = 0u; P4hi[nt] = 0u; }
    }

    // PV: build P A-frags via shuffles (no LDS), accumulate O
    f32x4 oacc[4];
    #pragma unroll
    for (int n = 0; n < 4; ++n) oacc[n] = (f32x4){0.f, 0.f, 0.f, 0.f};
    #pragma unroll
    for (int cpv = 0; cpv < 8; ++cpv) {
        if (cpv <= (MT >> 1)) {
            const unsigned a0 = __shfl(P4lo[2 * cpv],     srcA, 64);
            const unsigned a1 = __shfl(P4lo[2 * cpv + 1], srcA, 64);
            const unsigned b0 = __shfl(P4hi[2 * cpv],     srcA, 64);
            const unsigned b1 = __shfl(P4hi[2 * cpv + 1], srcA, 64);
            const unsigned c0 = __shfl(P4lo[2 * cpv],     srcB, 64);
            const unsigned c1 = __shfl(P4lo[2 * cpv + 1], srcB, 64);
            const unsigned d0 = __shfl(P4hi[2 * cpv],     srcB, 64);
            const unsigned d1 = __shfl(P4hi[2 * cpv + 1], srcB, 64);
            u32x4 wv;
            wv[0] = hi_half ? a1 : a0;
            wv[1] = hi_half ? b1 : b0;
            wv[2] = hi_half ? c1 : c0;
            wv[3] = hi_half ? d1 : d0;
            const bf16x8 pa = __builtin_bit_cast(bf16x8, wv);
            #pragma unroll
            for (int n = 0; n < 4; ++n) {
                const bf16x8 vb = *reinterpret_cast<const bf16x8*>(
                    &SM[FOFF_VT + (n * 16 + col) * FLDVT + cpv * 32 + g * 8]);
                oacc[n] = mfma16(pa, vb, oacc[n]);
            }
        }
    }

    // store O (P already normalized)
    #pragma unroll
    for (int n = 0; n < 4; ++n)
        #pragma unroll
        for (int r = 0; r < 4; ++r)
            out[((size_t)b * NT + MT * 16 + 4 * g + r) * NH + n * 16 + col] = oacc[n][r];
}

// ============ launcher =========================================================
extern "C" void kernel_launch(void* const* d_in, const int* in_sizes, int n_in,
                              void* d_out, int out_size, void* d_ws, size_t ws_size,
                              hipStream_t stream) {
    (void)in_sizes; (void)n_in; (void)out_size; (void)ws_size;
    const float* x  = (const float*)d_in[0];
    const float* wq = (const float*)d_in[1];
    const float* wk = (const float*)d_in[2];
    const float* wv = (const float*)d_in[3];
    float* o = (float*)d_out;

    unsigned short* Wf = (unsigned short*)d_ws;   // 147,456 B (ws is ~48 MB)
    prep_w <<<dim3(288), dim3(256),  0, stream>>>(wq, wk, wv, Wf);
    head_v4<<<dim3(NB),  dim3(1024), 0, stream>>>(x, Wf, o);
}